// Round 7
// baseline (101.064 us; speedup 1.0000x reference)
//
#include <hip/hip_runtime.h>
#include <math.h>

#define B_ 8
#define BIGF 3.4e38f

// ws layout: partial-min table only.
//   partial : SLICES x (B_*(N+M)) floats. partial[s][i] = min d^2 of query i
//             over ref-slice s. Every slot its slice-block covers is written
//             unconditionally (plain stores) -> NO init/memset needed.
// Ordering i: B_*N target queries, then B_*M source queries (as before).
//
// R7: dispatch-structure round. R0-R6 post-mortems: the minsq inner loop
// (LDS wave-uniform broadcast + 3 fma + min3/2pairs) resisted 6 mechanism
// changes (scalar-k$, readlane, pk_fma x2, SMEM, sw-pipeline) -- all
// neutral-or-worse; m07 calibration (scalar v_fma ubench = 65% of spec
// issue rate) puts the loop within ~1.5x of the empirical wall. The
// remaining measurable slack is the 5-dispatch stream (~10-12us of gaps +
// memsets). This round: same proven inner loop, but
//  (a) atomicMin-into-preinit-minarr -> plain per-slice partial stores
//      (kills both hipMemsetAsync nodes AND the 2M device-scope atomics),
//  (b) outp zeroed by a designated minsq block (reduce runs after),
//  (c) reduce min-combines the 32 slices per query (8 MiB L2-resident).
// Stream: fill(harness) + minsq + reduce = 2 launch gaps instead of 4.
template <int QPT, int CHUNK>
__global__ __launch_bounds__(256, 4) void minsq_kernel(
    const float* __restrict__ tar, const float* __restrict__ src,
    float* __restrict__ partial, float* __restrict__ outp, int N, int M)
{
    // Zero the 3 outputs once per launch (reduce is a later node on the same
    // stream; no minsq block touches outp otherwise -> race-free).
    if (blockIdx.x == 0 && blockIdx.y == 0 && blockIdx.z == 0 &&
        threadIdx.x < 3)
        outp[threadIdx.x] = 0.f;

    const int z   = blockIdx.z;
    const int dir = (z >= B_) ? 1 : 0;
    const int b   = dir ? (z - B_) : z;
    const float* __restrict__ qry = dir ? src : tar;   // raw float3 streams
    const float* __restrict__ pts = dir ? tar : src;
    const int K = dir ? M : N;   // query count
    const int L = dir ? N : M;   // reference count

    const int base = blockIdx.y * CHUNK;
    if (base >= L) return;
    const int cnt = min(CHUNK, L - base);

    // This slice's output row: partial[blockIdx.y][region + b*K + qi]
    const size_t SL = (size_t)B_ * (N + M);
    float* __restrict__ out = partial + (size_t)blockIdx.y * SL +
                              (dir ? (size_t)B_ * N : (size_t)0) +
                              (size_t)b * K;

    // Stage refs as float4 {x,y,z,|p|^2} (bitwise-identical fma form).
    __shared__ float4 sp[CHUNK];
    const float* __restrict__ p3 = pts + ((size_t)b * L + base) * 3;
    const int t = threadIdx.x;
    for (int i = t; i < cnt; i += 256) {
        float x = p3[3 * i], y = p3[3 * i + 1], zc = p3[3 * i + 2];
        sp[i] = make_float4(x, y, zc, fmaf(x, x, fmaf(y, y, zc * zc)));
    }
    __syncthreads();

    const float* __restrict__ q3 = qry + (size_t)b * K * 3;
    const int qbase = blockIdx.x * (256 * QPT);
    float qx2[QPT], qy2[QPT], qz2[QPT], qw[QPT], mn[QPT];
#pragma unroll
    for (int k = 0; k < QPT; ++k) {
        int qi = qbase + k * 256 + t;
        if (qi < K) {
            float x = q3[3 * qi], y = q3[3 * qi + 1], zc = q3[3 * qi + 2];
            qx2[k] = -2.f * x; qy2[k] = -2.f * y; qz2[k] = -2.f * zc;
            qw[k] = fmaf(x, x, fmaf(y, y, zc * zc));
        } else {
            qx2[k] = 0.f; qy2[k] = 0.f; qz2[k] = 0.f; qw[k] = 0.f;
        }
        mn[k] = BIGF;
    }

    if (cnt == CHUNK) {
#pragma unroll 4
        for (int j = 0; j < CHUNK; j += 2) {
            float4 p0 = sp[j];
            float4 p1 = sp[j + 1];
#pragma unroll
            for (int k = 0; k < QPT; ++k) {
                float d0 = fmaf(qx2[k], p0.x, fmaf(qy2[k], p0.y,
                           fmaf(qz2[k], p0.z, p0.w)));
                float d1 = fmaf(qx2[k], p1.x, fmaf(qy2[k], p1.y,
                           fmaf(qz2[k], p1.z, p1.w)));
                mn[k] = fminf(mn[k], fminf(d0, d1));   // v_min3_f32
            }
        }
    } else {
        // Generic tail (never taken for N=M=4096; kept for correctness).
        int j = 0;
        for (; j + 1 < cnt; j += 2) {
            float4 p0 = sp[j];
            float4 p1 = sp[j + 1];
#pragma unroll
            for (int k = 0; k < QPT; ++k) {
                float d0 = fmaf(qx2[k], p0.x, fmaf(qy2[k], p0.y,
                           fmaf(qz2[k], p0.z, p0.w)));
                float d1 = fmaf(qx2[k], p1.x, fmaf(qy2[k], p1.y,
                           fmaf(qz2[k], p1.z, p1.w)));
                mn[k] = fminf(mn[k], fminf(d0, d1));
            }
        }
        if (j < cnt) {
            float4 p0 = sp[j];
#pragma unroll
            for (int k = 0; k < QPT; ++k) {
                float d0 = fmaf(qx2[k], p0.x, fmaf(qy2[k], p0.y,
                           fmaf(qz2[k], p0.z, p0.w)));
                mn[k] = fminf(mn[k], d0);
            }
        }
    }

    // Plain coalesced stores: this (slice, query) slot belongs to exactly
    // this block. Clamp keeps sqrt safe in reduce.
#pragma unroll
    for (int k = 0; k < QPT; ++k) {
        int qi = qbase + k * 256 + t;
        if (qi < K) out[qi] = fmaxf(mn[k] + qw[k], 0.f);
    }
}

// Slice-combine + finalize: per query, min over its region's slice count,
// sqrt, stripe-sum; 3 scaled atomicAdds into outp (zeroed by minsq).
// 8 MiB of L2-resident reads across 64 blocks, fully coalesced per slice.
template <int CHUNK>
__global__ __launch_bounds__(256) void reduce_kernel(
    const float* __restrict__ partial, float* __restrict__ outp,
    int N, int M)
{
    const int nt = B_ * N, ns = B_ * M;
    const size_t SL = (size_t)nt + ns;
    const int slT = (M + CHUNK - 1) / CHUNK;  // tar queries ref into src
    const int slS = (N + CHUNK - 1) / CHUNK;  // src queries ref into tar
    const int gid = blockIdx.x * 256 + threadIdx.x;
    const int stride = gridDim.x * 256;
    float s_t = 0.f, s_s = 0.f;
    for (int i = gid; i < nt; i += stride) {
        float v = BIGF;
        for (int s = 0; s < slT; ++s)
            v = fminf(v, partial[(size_t)s * SL + i]);
        s_t += sqrtf(v);
    }
    for (int i = gid; i < ns; i += stride) {
        float v = BIGF;
        for (int s = 0; s < slS; ++s)
            v = fminf(v, partial[(size_t)s * SL + nt + i]);
        s_s += sqrtf(v);
    }
#pragma unroll
    for (int off = 32; off > 0; off >>= 1) {
        s_t += __shfl_down(s_t, off);
        s_s += __shfl_down(s_s, off);
    }
    __shared__ float rt[4], rs[4];
    const int wid = threadIdx.x >> 6, lid = threadIdx.x & 63;
    if (lid == 0) { rt[wid] = s_t; rs[wid] = s_s; }
    __syncthreads();
    if (threadIdx.x == 0) {
        float ct = (rt[0] + rt[1] + rt[2] + rt[3]) / (float)nt;  // complete
        float ac = (rs[0] + rs[1] + rs[2] + rs[3]) / (float)ns;  // accuracy
        atomicAdd(&outp[0], ac);
        atomicAdd(&outp[1], ct);
        atomicAdd(&outp[2], 0.5f * (ac + ct));
    }
}

extern "C" void kernel_launch(void* const* d_in, const int* in_sizes, int n_in,
                              void* d_out, int out_size, void* d_ws, size_t ws_size,
                              hipStream_t stream) {
    const float* tar = (const float*)d_in[0];
    const float* src = (const float*)d_in[1];
    const int N = in_sizes[0] / (B_ * 3);
    const int M = in_sizes[1] / (B_ * 3);

    float* partial = (float*)d_ws;
    float* outp = (float*)d_out;

    constexpr int QPT = 8, CHUNK = 128;
    const int KL = (N > M) ? N : M;
    const int gx = (KL + 256 * QPT - 1) / (256 * QPT);   // 2
    const int gy = (KL + CHUNK - 1) / CHUNK;             // 32
    dim3 grid(gx, gy, 2 * B_);                            // 1024 blocks
    minsq_kernel<QPT, CHUNK><<<grid, dim3(256), 0, stream>>>(
        tar, src, partial, outp, N, M);

    reduce_kernel<CHUNK><<<dim3(64), dim3(256), 0, stream>>>(
        partial, outp, N, M);
}